// Round 19
// baseline (666.375 us; speedup 1.0000x reference)
//
#include <hip/hip_runtime.h>
#include <cstdint>
#include <cstddef>

#define N_NODES   100000
#define M_PAD     100096   // 782 * 128
#define DIM       256
#define NTYPES    6
#define M_EDGES   400000
#define TOTAL_E   2400000
#define C_COPY    16       // edge segments (copies)
#define SEG       150000   // TOTAL_E / C_COPY
#define R_RANGE   8        // tgt ranges
#define RNG       12500    // N_NODES / R_RANGE
#define NSCAN     1600000  // C_COPY * N_NODES, lin = c*N_NODES + tgt
#define SCAN_BLKS 1563     // ceil(NSCAN/1024)
#define GEMM_BLKS 4704     // 98 * 48

typedef _Float16 f16x8 __attribute__((ext_vector_type(8)));
typedef _Float16 f16x2 __attribute__((ext_vector_type(2)));
typedef float    f32x4 __attribute__((ext_vector_type(4)));

// ==== fused prep: [b16 192 | gating 512 | a16 aBlk]  (no hist!) =============
__global__ void prep_kernel(const float* __restrict__ x, _Float16* __restrict__ Ap,
                            const float* __restrict__ W, _Float16* __restrict__ Bp,
                            const float* __restrict__ Wp, const float* __restrict__ bp,
                            _Float16* __restrict__ gateb)
{
    int b = blockIdx.x;
    if (b < 192){
        // ---- B16 = fp16(W) ----
        int tid = b * 256 + threadIdx.x;
        int idx = tid << 3;
        const f32x4* pw = (const f32x4*)(W + idx);
        f32x4 v0 = __builtin_nontemporal_load(pw);
        f32x4 v1 = __builtin_nontemporal_load(pw + 1);
        f16x8 h;
        h[0]=(_Float16)v0[0]; h[1]=(_Float16)v0[1]; h[2]=(_Float16)v0[2]; h[3]=(_Float16)v0[3];
        h[4]=(_Float16)v1[0]; h[5]=(_Float16)v1[1]; h[6]=(_Float16)v1[2]; h[7]=(_Float16)v1[3];
        *(f16x8*)(Bp + idx) = h;
    } else if (b < 704){
        // ---- gating table, fp64 trig ----
        __shared__ float semb[256];
        int p = b - 192;     // 0..511
        int t = threadIdx.x;
        if (t < 127){
            double invf = exp(-log(10000.0) * (2.0 * t) / 254.0);
            double a = (double)p * invf;
            semb[t]       = (float)sin(a);
            semb[t + 127] = (float)cos(a);
        } else if (t >= 254){
            semb[t] = 0.0f;
        }
        __syncthreads();
        float z = bp[t];
        const float* wr = Wp + (size_t)t * 256;
        #pragma unroll 4
        for (int kq = 0; kq < 256; ++kq) z += semb[kq] * wr[kq];
        gateb[(size_t)p * 256 + t] = (_Float16)(2.0f / (1.0f + expf(-z)));
    } else {
        // ---- A16 = fp16(X) ----
        int tid = (b - 704) * 256 + threadIdx.x;
        int idx = tid << 3;
        int row = idx >> 8;
        int k   = idx & 255;
        f16x8 h;
        if (row < N_NODES){
            const f32x4* px = (const f32x4*)(x + (size_t)row * DIM + k);
            f32x4 v0 = __builtin_nontemporal_load(px);
            f32x4 v1 = __builtin_nontemporal_load(px + 1);
            h[0]=(_Float16)v0[0]; h[1]=(_Float16)v0[1]; h[2]=(_Float16)v0[2]; h[3]=(_Float16)v0[3];
            h[4]=(_Float16)v1[0]; h[5]=(_Float16)v1[1]; h[6]=(_Float16)v1[2]; h[7]=(_Float16)v1[3];
        } else {
            #pragma unroll
            for (int j = 0; j < 8; ++j) h[j] = (_Float16)0.f;
        }
        *(f16x8*)(Ap + (size_t)row * 256 + k) = h;
    }
}

// ==== LDS histogram: block (r,c) counts segment c's edges in tgt-range r ====
// Zero global atomics; every buf slot written exactly once (no memset needed).
__global__ __launch_bounds__(1024) void hist_lds(const int* __restrict__ edges,
                                                 int* __restrict__ buf){
    __shared__ int cnt[RNG];
    const int c = blockIdx.x & 15;
    const int r = blockIdx.x >> 4;
    const int tid = threadIdx.x;
    for (int i = tid; i < RNG; i += 1024) cnt[i] = 0;
    __syncthreads();
    const int lo = r * RNG;
    const int s0 = c * SEG, s1 = s0 + SEG;
    for (int e0 = s0; e0 < s1; e0 += 4096){
        #pragma unroll
        for (int j = 0; j < 4; ++j){
            int e = e0 + (j << 10) + tid;
            if (e < s1){
                int t = edges[(size_t)e * 2 + 1];
                unsigned d = (unsigned)(t - lo);
                if (d < RNG) atomicAdd(&cnt[d], 1);
            }
        }
    }
    __syncthreads();
    int* dst = buf + c * N_NODES + lo;
    for (int i = tid; i < RNG; i += 1024) dst[i] = cnt[i];
}

__global__ void scan1_kernel(int* __restrict__ buf, int* __restrict__ bsum){
    __shared__ int lds[256];
    int t = threadIdx.x;
    int base = blockIdx.x * 1024 + t * 4;
    int v[4]; int s = 0;
    #pragma unroll
    for (int j = 0; j < 4; ++j){
        int i = base + j;
        int val = (i < NSCAN) ? buf[i] : 0;
        v[j] = val; s += val;
    }
    lds[t] = s; __syncthreads();
    for (int d = 1; d < 256; d <<= 1){
        int xv = (t >= d) ? lds[t - d] : 0;
        __syncthreads();
        lds[t] += xv;
        __syncthreads();
    }
    int run = (t > 0) ? lds[t - 1] : 0;
    #pragma unroll
    for (int j = 0; j < 4; ++j){ int i = base + j; if (i < NSCAN) buf[i] = run; run += v[j]; }
    if (t == 255) bsum[blockIdx.x] = run;
}

__global__ void scan2_kernel(const int* __restrict__ bsum, int* __restrict__ ssum){
    __shared__ int lds[256];
    __shared__ int carry;
    int t = threadIdx.x;
    if (t == 0) carry = 0;
    __syncthreads();
    for (int ch = 0; ch < 7; ++ch){
        int idx = ch * 256 + t;
        int v = (idx < SCAN_BLKS) ? bsum[idx] : 0;
        lds[t] = v; __syncthreads();
        for (int d = 1; d < 256; d <<= 1){
            int xv = (t >= d) ? lds[t - d] : 0;
            __syncthreads();
            lds[t] += xv;
            __syncthreads();
        }
        int ex = carry + ((t > 0) ? lds[t - 1] : 0);
        if (idx < SCAN_BLKS) ssum[idx] = ex;
        __syncthreads();
        if (t == 255) carry += lds[255];
        __syncthreads();
    }
}

__global__ void scan3_kernel(int* __restrict__ buf, const int* __restrict__ ssum){
    int i = blockIdx.x * 256 + threadIdx.x;   // NSCAN exact (6250*256)
    buf[i] += ssum[i >> 10];
    if (i == 0) buf[NSCAN] = TOTAL_E;         // sentinel
}

// ==== LDS-cursor scatter: zero global atomics ===============================
__global__ __launch_bounds__(1024) void scatter_lds(const int* __restrict__ edges,
                                                    const int* __restrict__ posl,
                                                    const int* __restrict__ buf,
                                                    unsigned* __restrict__ packed){
    __shared__ int cur[RNG];
    const int c = blockIdx.x & 15;
    const int r = blockIdx.x >> 4;
    const int tid = threadIdx.x;
    const int lo = r * RNG;
    const int* off = buf + c * N_NODES + lo;
    for (int i = tid; i < RNG; i += 1024) cur[i] = off[i];
    __syncthreads();
    const int s0 = c * SEG, s1 = s0 + SEG;
    for (int e0 = s0; e0 < s1; e0 += 4096){
        #pragma unroll
        for (int j = 0; j < 4; ++j){
            int e = e0 + (j << 10) + tid;
            if (e < s1){
                int2 ed = *(const int2*)(edges + (size_t)e * 2);
                unsigned d = (unsigned)(ed.y - lo);
                if (d < RNG){
                    int p = atomicAdd(&cur[d], 1);
                    int type = e / M_EDGES;
                    packed[p] = (unsigned)ed.x | ((unsigned)posl[e] << 17)
                              | ((unsigned)type << 26);
                }
            }
        }
    }
}

// ==== cooperative GEMM epilogue: 64-row shared stage, 1KB-contiguous nt stores
__device__ __forceinline__ void gemm_epilogue(
        char* smem, f32x4 (&acc)[4][4], const float* bbase, _Float16* propD,
        int t, size_t m0, int lane, int wid, int wr, int wc)
{
    float bv[4];
    #pragma unroll
    for (int n = 0; n < 4; ++n)
        bv[n] = bbase[(size_t)t * 256 + (wc << 6) + (n << 4) + (lane & 15)];

    const int q  = lane >> 4;          // 0..3
    const int li = lane & 15;
    const int cb = wid & 1;            // dim-block
    const int w2 = wid >> 1;           // 0..3

    #pragma unroll
    for (int ph = 0; ph < 2; ++ph){
        __syncthreads();
        if (wr == ph){
            #pragma unroll
            for (int m = 0; m < 4; ++m){
                #pragma unroll
                for (int n = 0; n < 4; ++n){
                    #pragma unroll
                    for (int j = 0; j < 4; ++j){
                        int lrow = (m << 4) + (q << 2) + j;          // (lrow>>2)&3 == q
                        int b    = (((wc << 6) + (n << 4) + li) << 1) ^ (q << 5);
                        *(_Float16*)(smem + lrow * 512 + b) =
                            (_Float16)(acc[m][n][j] + bv[n]);
                    }
                }
            }
        }
        __syncthreads();
        #pragma unroll
        for (int it = 0; it < 4; ++it){
            int r4   = w2 + (it << 2);          // 0..15
            int lrow = (r4 << 2) + q;           // (lrow>>2)&3 == r4&3
            int b    = ((cb << 8) + (li << 4)) ^ ((r4 & 3) << 5);
            f16x8 v = *(const f16x8*)(smem + lrow * 512 + b);
            size_t grow = m0 + (size_t)(ph << 6) + (size_t)lrow;
            _Float16* dst = propD + ((size_t)(cb * NTYPES + t) * M_PAD + grow) * 128
                            + (li << 3);
            __builtin_nontemporal_store(v, (f16x8*)dst);
        }
    }
}

__device__ __forceinline__ void gemm_mfma_phase(
        char* smem, f32x4 (&acc)[4][4], int lane, int wr, int wc)
{
    _Float16* sA = (_Float16*)smem;
    _Float16* sB = (_Float16*)(smem + 16384);
    #pragma unroll
    for (int ks = 0; ks < 2; ++ks){
        int slot = (ks << 6) + ((lane >> 4) << 4);
        f16x8 af[4];
        #pragma unroll
        for (int m = 0; m < 4; ++m){
            int rA = (wr << 6) + (m << 4) + (lane & 15);
            af[m] = *(const f16x8*)((const char*)sA + rA * 128 + (slot ^ ((rA & 7) << 4)));
        }
        #pragma unroll
        for (int n = 0; n < 4; ++n){
            int rB = (wc << 6) + (n << 4) + (lane & 15);
            f16x8 bfr = *(const f16x8*)((const char*)sB + rB * 128 + (slot ^ ((rB & 7) << 4)));
            #pragma unroll
            for (int m = 0; m < 4; ++m)
                acc[m][n] = __builtin_amdgcn_mfma_f32_16x16x32_f16(af[m], bfr, acc[m][n], 0, 0, 0);
        }
    }
}

// ---- plan-A GEMM: all 6 types, A from fp16 Ap via global_load_lds ----------
__global__ __launch_bounds__(512, 4) void gemm_ap(
        const _Float16* __restrict__ Ap,
        const _Float16* __restrict__ Bp,
        const float* __restrict__ bbase,
        _Float16* __restrict__ propD)
{
    __shared__ __align__(16) char smem[49152];
    const int bid = blockIdx.x;
    const int g   = bid / 48;
    const int r   = bid - g * 48;
    const int rp  = g * 8 + (r & 7);
    const int t   = r >> 3;                 // 0..5
    if (rp >= 782) return;
    const int tid  = threadIdx.x;
    const int lane = tid & 63;
    const int wid  = tid >> 6;
    const int wr   = wid >> 2;
    const int wc   = wid & 3;
    const size_t m0 = (size_t)rp * 128;
    const _Float16* Bt = Bp + (size_t)t * 256 * 256;

    f32x4 acc[4][4];
    #pragma unroll
    for (int m = 0; m < 4; ++m)
        #pragma unroll
        for (int n = 0; n < 4; ++n)
            acc[m][n] = (f32x4){0.f, 0.f, 0.f, 0.f};

    const int sub  = lane >> 3;
    const int bib  = (lane & 7) << 4;
    const int soff = bib ^ (sub << 4);

    for (int kk = 0; kk < 4; ++kk){
        #pragma unroll
        for (int ci = 0; ci < 6; ++ci){
            int c = wid * 6 + ci;
            const char* gsrc;
            char* ldst;
            if (c < 16){
                gsrc = (const char*)(Ap + (m0 + (size_t)((c << 3) + sub)) * 256);
                ldst = (char*)smem + (c << 10);
            } else {
                int c2 = c - 16;
                gsrc = (const char*)(Bt + ((size_t)(c2 << 3) + sub) * 256);
                ldst = (char*)smem + 16384 + (c2 << 10);
            }
            __builtin_amdgcn_global_load_lds(
                (const __attribute__((address_space(1))) void*)(gsrc + (kk << 7) + soff),
                (__attribute__((address_space(3))) void*)ldst, 16, 0, 0);
        }
        __syncthreads();
        gemm_mfma_phase(smem, acc, lane, wr, wc);
        __syncthreads();
    }
    gemm_epilogue(smem, acc, bbase, propD, t, m0, lane, wid, wr, wc);
}

// ---- plan-B GEMM: A reg-staged from fp32 x (no Ap buffer needed) -----------
__global__ __launch_bounds__(512, 4) void gemm_dx(
        const float* __restrict__ x,
        const _Float16* __restrict__ Bp,
        const float* __restrict__ bbase,
        _Float16* __restrict__ propD)
{
    __shared__ __align__(16) char smem[49152];
    _Float16* sA = (_Float16*)smem;
    const int bid = blockIdx.x;
    const int g   = bid / 48;
    const int r   = bid - g * 48;
    const int rp  = g * 8 + (r & 7);
    const int t   = r >> 3;
    if (rp >= 782) return;
    const int tid  = threadIdx.x;
    const int lane = tid & 63;
    const int wid  = tid >> 6;
    const int wr   = wid >> 2;
    const int wc   = wid & 3;
    const size_t m0 = (size_t)rp * 128;
    const _Float16* Bt = Bp + (size_t)t * 256 * 256;

    f32x4 acc[4][4];
    #pragma unroll
    for (int m = 0; m < 4; ++m)
        #pragma unroll
        for (int n = 0; n < 4; ++n)
            acc[m][n] = (f32x4){0.f, 0.f, 0.f, 0.f};

    const int sub  = lane >> 3;
    const int bib  = (lane & 7) << 4;
    const int soff = bib ^ (sub << 4);

    for (int kk = 0; kk < 4; ++kk){
        #pragma unroll
        for (int ci = 0; ci < 6; ++ci){
            int c = wid * 6 + ci;
            if (c < 16){
                int rr = (c << 3) + sub;
                size_t grow = m0 + (size_t)rr;
                f32x4 u0 = (f32x4){0.f,0.f,0.f,0.f};
                f32x4 u1 = (f32x4){0.f,0.f,0.f,0.f};
                if (grow < N_NODES){
                    const float* px = x + grow * 256 + (kk << 6) + ((lane & 7) << 3);
                    u0 = *(const f32x4*)px;
                    u1 = *(const f32x4*)(px + 4);
                }
                f16x8 hv;
                hv[0]=(_Float16)u0[0]; hv[1]=(_Float16)u0[1];
                hv[2]=(_Float16)u0[2]; hv[3]=(_Float16)u0[3];
                hv[4]=(_Float16)u1[0]; hv[5]=(_Float16)u1[1];
                hv[6]=(_Float16)u1[2]; hv[7]=(_Float16)u1[3];
                *(f16x8*)((char*)sA + rr * 128 + (bib ^ (sub << 4))) = hv;
            } else {
                int c2 = c - 16;
                const char* gsrc = (const char*)(Bt + ((size_t)(c2 << 3) + sub) * 256);
                char* ldst = (char*)smem + 16384 + (c2 << 10);
                __builtin_amdgcn_global_load_lds(
                    (const __attribute__((address_space(1))) void*)(gsrc + (kk << 7) + soff),
                    (__attribute__((address_space(3))) void*)ldst, 16, 0, 0);
            }
        }
        __syncthreads();
        gemm_mfma_phase(smem, acc, lane, wr, wc);
        __syncthreads();
    }
    gemm_epilogue(smem, acc, bbase, propD, t, m0, lane, wid, wr, wc);
}

// ---- dim-half aggregation: 16 copies, start-offsets + sentinel, ILP-4 ------
__global__ void aggregate(const _Float16* __restrict__ propD, const _Float16* __restrict__ gate,
                          const unsigned* __restrict__ packed,
                          const int* __restrict__ buf,
                          int dh, float* __restrict__ out)
{
    int tgt  = blockIdx.x * 4 + (threadIdx.x >> 6);
    int lane = threadIdx.x & 63;

    int dd[C_COPY], P[C_COPY + 1];
    P[0] = 0;
    #pragma unroll
    for (int c = 0; c < C_COPY; ++c){
        int lin = c * N_NODES + tgt;
        int a0 = buf[lin];
        int a1 = buf[lin + 1];
        dd[c] = a0 - P[c];
        P[c + 1] = P[c] + (a1 - a0);
    }
    int n = P[C_COPY];

    const _Float16* pbase = propD + (size_t)dh * NTYPES * M_PAD * 128;
    const _Float16* gbase = gate + dh * 128;

    float a0x = 0.f, a0y = 0.f, a1x = 0.f, a1y = 0.f;
    float a2x = 0.f, a2y = 0.f, a3x = 0.f, a3y = 0.f;

    for (int c0 = 0; c0 < n; c0 += 64){
        int e = c0 + lane;
        int idx = dd[0] + e;
        #pragma unroll
        for (int c = 1; c < C_COPY; ++c)
            if (e >= P[c]) idx = dd[c] + e;
        unsigned wv = (e < n) ? packed[idx] : 0u;
        int m = n - c0; if (m > 64) m = 64;
        int e2 = 0;
        for (; e2 + 3 < m; e2 += 4){
            unsigned w[4];
            #pragma unroll
            for (int j = 0; j < 4; ++j)
                w[j] = (unsigned)__builtin_amdgcn_readlane((int)wv, e2 + j);
            f16x2 pv[4], gv[4];
            #pragma unroll
            for (int j = 0; j < 4; ++j){
                int src = (int)(w[j] & 0x1FFFFu);
                int pz  = (int)((w[j] >> 17) & 0x1FFu);
                int ty  = (int)(w[j] >> 26);
                pv[j] = *(const f16x2*)(pbase + ((size_t)ty * M_PAD + (size_t)src) * 128 + lane * 2);
                gv[j] = *(const f16x2*)(gbase + (size_t)pz * 256 + lane * 2);
            }
            a0x += (float)pv[0][0] * (float)gv[0][0];
            a0y += (float)pv[0][1] * (float)gv[0][1];
            a1x += (float)pv[1][0] * (float)gv[1][0];
            a1y += (float)pv[1][1] * (float)gv[1][1];
            a2x += (float)pv[2][0] * (float)gv[2][0];
            a2y += (float)pv[2][1] * (float)gv[2][1];
            a3x += (float)pv[3][0] * (float)gv[3][0];
            a3y += (float)pv[3][1] * (float)gv[3][1];
        }
        for (; e2 < m; ++e2){
            unsigned w0 = (unsigned)__builtin_amdgcn_readlane((int)wv, e2);
            int src = (int)(w0 & 0x1FFFFu);
            int pz  = (int)((w0 >> 17) & 0x1FFu);
            int ty  = (int)(w0 >> 26);
            f16x2 pv = *(const f16x2*)(pbase + ((size_t)ty * M_PAD + (size_t)src) * 128 + lane * 2);
            f16x2 gv = *(const f16x2*)(gbase + (size_t)pz * 256 + lane * 2);
            a0x += (float)pv[0] * (float)gv[0];
            a0y += (float)pv[1] * (float)gv[1];
        }
    }
    a0x += a1x + a2x + a3x;
    a0y += a1y + a2y + a3y;
    float inv = ((n == 0) ? 1.0f : (float)n) + 1e-8f;
    float2 rr = make_float2(a0x / inv, a0y / inv);
    *(float2*)(out + (size_t)tgt * DIM + dh * 128 + lane * 2) = rr;
}

extern "C" void kernel_launch(void* const* d_in, const int* in_sizes, int n_in,
                              void* d_out, int out_size, void* d_ws, size_t ws_size,
                              hipStream_t stream)
{
    const float* x     = (const float*)d_in[0];
    const float* W     = (const float*)d_in[1];
    const float* b     = (const float*)d_in[2];
    const float* Wp    = (const float*)d_in[3];
    const float* bp    = (const float*)d_in[4];
    const int*   edges = (const int*)d_in[5];
    const int*   posl  = (const int*)d_in[6];
    float* out = (float*)d_out;

    char* ws = (char*)d_ws;
    size_t o = 0;
    auto alloc = [&](size_t bytes){ void* p = ws + o; o += (bytes + 255) & ~(size_t)255; return p; };

    _Float16* propD = (_Float16*)alloc((size_t)2 * NTYPES * M_PAD * 128 * 2);  // 307.5 MB
    _Float16* Bp    = (_Float16*)alloc((size_t)NTYPES * 256 * 256 * 2);
    _Float16* gate  = (_Float16*)alloc((size_t)512 * 256 * 2);
    int*      buf   = (int*)alloc((size_t)(NSCAN + 1) * 4);    // counts->start offs
    unsigned* packed= (unsigned*)alloc((size_t)TOTAL_E * 4);
    int*      bsum  = (int*)alloc((size_t)SCAN_BLKS * 4 + 256);
    int*      ssum  = (int*)alloc((size_t)SCAN_BLKS * 4 + 256);

    size_t apBytes = (size_t)M_PAD * 256 * 2;                  // 51.25 MB
    bool planA = (ws_size >= o + apBytes + 1024);
    _Float16* Ap = planA ? (_Float16*)alloc(apBytes) : nullptr;
    int aBlk = planA ? 12512 : 0;

    prep_kernel<<<704 + aBlk, 256, 0, stream>>>(x, Ap, W, Bp, Wp, bp, gate);
    hist_lds<<<128, 1024, 0, stream>>>(edges, buf);
    scan1_kernel<<<SCAN_BLKS, 256, 0, stream>>>(buf, bsum);
    scan2_kernel<<<1, 256, 0, stream>>>(bsum, ssum);
    scan3_kernel<<<6250, 256, 0, stream>>>(buf, ssum);
    scatter_lds<<<128, 1024, 0, stream>>>(edges, posl, buf, packed);

    if (planA) gemm_ap<<<GEMM_BLKS, 512, 0, stream>>>(Ap, Bp, b, propD);
    else       gemm_dx<<<GEMM_BLKS, 512, 0, stream>>>(x, Bp, b, propD);

    aggregate<<<25000, 256, 0, stream>>>(propD, gate, packed, buf, 0, out);
    aggregate<<<25000, 256, 0, stream>>>(propD, gate, packed, buf, 1, out);
}

// Round 20
// 558.825 us; speedup vs baseline: 1.1925x; 1.1925x over previous
//
#include <hip/hip_runtime.h>
#include <cstdint>
#include <cstddef>

#define N_NODES   100000
#define M_PAD     100096   // 782 * 128
#define DIM       256
#define NTYPES    6
#define M_EDGES   400000
#define TOTAL_E   2400000
#define EIGHTH_E  300000
#define NCOPY     8
#define NSCAN     800000   // NCOPY * N_NODES, lin = c*N_NODES + tgt
#define SCAN_BLKS 782      // ceil(NSCAN/1024)
#define GEMM_BLKS 4704     // 98 * 48
#define PWAVE     2000     // partition waves (125 blocks * 16)
#define WSEG      1200     // TOTAL_E / PWAVE
#define NPART     16000    // 8 ranges * PWAVE
#define RNG       12500    // N_NODES / 8

typedef _Float16 f16x8 __attribute__((ext_vector_type(8)));
typedef _Float16 f16x2 __attribute__((ext_vector_type(2)));
typedef float    f32x4 __attribute__((ext_vector_type(4)));

// ==== fused prep (no hist): [b16 192 | gating 512 | a16 aBlk] ===============
__global__ void prep_kernel(const float* __restrict__ x, _Float16* __restrict__ Ap,
                            const float* __restrict__ W, _Float16* __restrict__ Bp,
                            const float* __restrict__ Wp, const float* __restrict__ bp,
                            _Float16* __restrict__ gateb)
{
    int b = blockIdx.x;
    if (b < 192){
        int tid = b * 256 + threadIdx.x;
        int idx = tid << 3;
        const f32x4* pw = (const f32x4*)(W + idx);
        f32x4 v0 = __builtin_nontemporal_load(pw);
        f32x4 v1 = __builtin_nontemporal_load(pw + 1);
        f16x8 h;
        h[0]=(_Float16)v0[0]; h[1]=(_Float16)v0[1]; h[2]=(_Float16)v0[2]; h[3]=(_Float16)v0[3];
        h[4]=(_Float16)v1[0]; h[5]=(_Float16)v1[1]; h[6]=(_Float16)v1[2]; h[7]=(_Float16)v1[3];
        *(f16x8*)(Bp + idx) = h;
    } else if (b < 704){
        __shared__ float semb[256];
        int p = b - 192;
        int t = threadIdx.x;
        if (t < 127){
            double invf = exp(-log(10000.0) * (2.0 * t) / 254.0);
            double a = (double)p * invf;
            semb[t]       = (float)sin(a);
            semb[t + 127] = (float)cos(a);
        } else if (t >= 254){
            semb[t] = 0.0f;
        }
        __syncthreads();
        float z = bp[t];
        const float* wr = Wp + (size_t)t * 256;
        #pragma unroll 4
        for (int kq = 0; kq < 256; ++kq) z += semb[kq] * wr[kq];
        gateb[(size_t)p * 256 + t] = (_Float16)(2.0f / (1.0f + expf(-z)));
    } else {
        int tid = (b - 704) * 256 + threadIdx.x;
        int idx = tid << 3;
        int row = idx >> 8;
        int k   = idx & 255;
        f16x8 h;
        if (row < N_NODES){
            const f32x4* px = (const f32x4*)(x + (size_t)row * DIM + k);
            f32x4 v0 = __builtin_nontemporal_load(px);
            f32x4 v1 = __builtin_nontemporal_load(px + 1);
            h[0]=(_Float16)v0[0]; h[1]=(_Float16)v0[1]; h[2]=(_Float16)v0[2]; h[3]=(_Float16)v0[3];
            h[4]=(_Float16)v1[0]; h[5]=(_Float16)v1[1]; h[6]=(_Float16)v1[2]; h[7]=(_Float16)v1[3];
        } else {
            #pragma unroll
            for (int j = 0; j < 8; ++j) h[j] = (_Float16)0.f;
        }
        *(f16x8*)(Ap + (size_t)row * 256 + k) = h;
    }
}

// ==== wave-level radix partition by tgt-range (zero atomics) ================
__global__ __launch_bounds__(1024) void part_count(const int* __restrict__ edges,
                                                   int* __restrict__ cnt0){
    int g = blockIdx.x * 16 + (threadIdx.x >> 6);   // 0..1999
    int lane = threadIdx.x & 63;
    int base = g * WSEG;
    int cnt[8];
    #pragma unroll
    for (int r = 0; r < 8; ++r) cnt[r] = 0;
    for (int it = 0; it < WSEG; it += 64){
        bool act = (it + lane) < WSEG;
        int r = 8;
        if (act) r = (int)((unsigned)edges[(size_t)(base + it + lane) * 2 + 1] / 12500u);
        #pragma unroll
        for (int rr = 0; rr < 8; ++rr)
            cnt[rr] += (int)__popcll(__ballot(r == rr));
    }
    if (lane < 8) cnt0[lane * PWAVE + g] = cnt[lane];
}

__global__ __launch_bounds__(1024) void part_scan(const int* __restrict__ cnt0,
                                                  int* __restrict__ off0){
    __shared__ int lds[1024];
    int t = threadIdx.x;
    int v[16]; int s = 0;
    if (t < 1000){
        #pragma unroll
        for (int j = 0; j < 16; ++j){ v[j] = cnt0[t * 16 + j]; s += v[j]; }
    }
    lds[t] = s; __syncthreads();
    for (int d = 1; d < 1024; d <<= 1){
        int xv = (t >= d) ? lds[t - d] : 0;
        __syncthreads();
        lds[t] += xv;
        __syncthreads();
    }
    if (t < 1000){
        int run = t ? lds[t - 1] : 0;
        #pragma unroll
        for (int j = 0; j < 16; ++j){ off0[t * 16 + j] = run; run += v[j]; }
    }
    if (t == 0) off0[NPART] = TOTAL_E;
}

__global__ __launch_bounds__(1024) void part_scatter(const int* __restrict__ edges,
                                                     const int* __restrict__ posl,
                                                     const int* __restrict__ off0,
                                                     int2* __restrict__ part){
    int g = blockIdx.x * 16 + (threadIdx.x >> 6);
    int lane = threadIdx.x & 63;
    int base = g * WSEG;
    int cur[8];
    #pragma unroll
    for (int r = 0; r < 8; ++r) cur[r] = off0[r * PWAVE + g];
    unsigned long long ltm = (lane == 63) ? 0x7FFFFFFFFFFFFFFFull
                                          : ((1ull << lane) - 1ull);
    for (int it = 0; it < WSEG; it += 64){
        int e = base + it + lane;
        bool act = (it + lane) < WSEG;
        int r = 8; int2 ed = make_int2(0, 0); int pz = 0;
        if (act){
            ed = *(const int2*)(edges + (size_t)e * 2);
            pz = posl[e];
            r = (int)((unsigned)ed.y / 12500u);
        }
        int type = e / M_EDGES;
        unsigned pay = (unsigned)ed.x | ((unsigned)pz << 17) | ((unsigned)type << 26);
        #pragma unroll
        for (int rr = 0; rr < 8; ++rr){
            unsigned long long m = __ballot(r == rr);
            if (r == rr)
                part[cur[rr] + (int)__popcll(m & ltm)] = make_int2((int)pay, ed.y);
            cur[rr] += (int)__popcll(m);
        }
    }
}

// ==== range-local LDS hist: block (r,s) owns contiguous slice of part =======
__global__ __launch_bounds__(1024) void hist_lds2(const int2* __restrict__ part,
                                                  const int* __restrict__ off0,
                                                  int* __restrict__ buf){
    __shared__ int cnt[RNG];
    int r = blockIdx.x >> 3, s = blockIdx.x & 7;
    int t = threadIdx.x;
    for (int i = t; i < RNG; i += 1024) cnt[i] = 0;
    __syncthreads();
    int rb = off0[r * PWAVE];
    int re = off0[(r + 1) * PWAVE];
    long len = (long)(re - rb);
    int s0 = rb + (int)(len * s / 8);
    int s1 = rb + (int)(len * (s + 1) / 8);
    int lo = r * RNG;
    for (int i = s0 + t; i < s1; i += 1024)
        atomicAdd(&cnt[part[i].y - lo], 1);
    __syncthreads();
    int* dst = buf + s * N_NODES + lo;
    for (int i = t; i < RNG; i += 1024) dst[i] = cnt[i];
}

// ==== scans over 800K counts -> start offsets (+sentinel, optional cursor) ==
__global__ void scan1_kernel(int* __restrict__ buf, int* __restrict__ bsum){
    __shared__ int lds[256];
    int t = threadIdx.x;
    int base = blockIdx.x * 1024 + t * 4;
    int v[4]; int s = 0;
    #pragma unroll
    for (int j = 0; j < 4; ++j){
        int i = base + j;
        int val = (i < NSCAN) ? buf[i] : 0;
        v[j] = val; s += val;
    }
    lds[t] = s; __syncthreads();
    for (int d = 1; d < 256; d <<= 1){
        int xv = (t >= d) ? lds[t - d] : 0;
        __syncthreads();
        lds[t] += xv;
        __syncthreads();
    }
    int run = (t > 0) ? lds[t - 1] : 0;
    #pragma unroll
    for (int j = 0; j < 4; ++j){ int i = base + j; if (i < NSCAN) buf[i] = run; run += v[j]; }
    if (t == 255) bsum[blockIdx.x] = run;
}

__global__ void scan2_kernel(const int* __restrict__ bsum, int* __restrict__ ssum){
    __shared__ int lds[256];
    __shared__ int carry;
    int t = threadIdx.x;
    if (t == 0) carry = 0;
    __syncthreads();
    for (int ch = 0; ch < 4; ++ch){
        int idx = ch * 256 + t;
        int v = (idx < SCAN_BLKS) ? bsum[idx] : 0;
        lds[t] = v; __syncthreads();
        for (int d = 1; d < 256; d <<= 1){
            int xv = (t >= d) ? lds[t - d] : 0;
            __syncthreads();
            lds[t] += xv;
            __syncthreads();
        }
        int ex = carry + ((t > 0) ? lds[t - 1] : 0);
        if (idx < SCAN_BLKS) ssum[idx] = ex;
        __syncthreads();
        if (t == 255) carry += lds[255];
        __syncthreads();
    }
}

__global__ void scan3_kernel(int* __restrict__ buf, const int* __restrict__ ssum,
                             int* __restrict__ cursor){
    int i = blockIdx.x * 256 + threadIdx.x;   // NSCAN exact (3125*256)
    int vv = buf[i] + ssum[i >> 10];
    buf[i] = vv;
    if (cursor) cursor[i] = vv;
    if (i == 0) buf[NSCAN] = TOTAL_E;         // sentinel
}

// ==== range-local LDS-cursor scatter (zero global atomics) ==================
__global__ __launch_bounds__(1024) void scatter_lds2(const int2* __restrict__ part,
                                                     const int* __restrict__ off0,
                                                     const int* __restrict__ buf,
                                                     unsigned* __restrict__ packed){
    __shared__ int cur[RNG];
    int r = blockIdx.x >> 3, s = blockIdx.x & 7;
    int t = threadIdx.x;
    int lo = r * RNG;
    const int* off = buf + s * N_NODES + lo;
    for (int i = t; i < RNG; i += 1024) cur[i] = off[i];
    __syncthreads();
    int rb = off0[r * PWAVE];
    int re = off0[(r + 1) * PWAVE];
    long len = (long)(re - rb);
    int s0 = rb + (int)(len * s / 8);
    int s1 = rb + (int)(len * (s + 1) / 8);
    for (int i = s0 + t; i < s1; i += 1024){
        int2 pe = part[i];
        int p = atomicAdd(&cur[pe.y - lo], 1);
        packed[p] = (unsigned)pe.x;
    }
}

// ==== planA fallback: global-atomic hist & scatter ==========================
__global__ void hist_glob(const int* __restrict__ edges, int* __restrict__ buf){
    int t0 = blockIdx.x * 256 + threadIdx.x;
    if (t0 >= EIGHTH_E) return;
    int copy = blockIdx.x & 7;
    #pragma unroll
    for (int j = 0; j < 8; ++j){
        int e = t0 + j * EIGHTH_E;
        int tgt = edges[(size_t)e * 2 + 1];
        atomicAdd(buf + copy * N_NODES + tgt, 1);
    }
}

__global__ void scatter_glob(const int* __restrict__ edges, const int* __restrict__ posl,
                             int* __restrict__ cursor, unsigned* __restrict__ packed){
    int t0 = blockIdx.x * 256 + threadIdx.x;
    if (t0 >= EIGHTH_E) return;
    int copy = blockIdx.x & 7;
    #pragma unroll
    for (int j = 0; j < 8; ++j){
        int e = t0 + j * EIGHTH_E;
        int type = e / M_EDGES;
        int2 ed = *(const int2*)(edges + (size_t)e * 2);
        int p = atomicAdd(cursor + copy * N_NODES + ed.y, 1);
        packed[p] = (unsigned)ed.x | ((unsigned)posl[e] << 17) | ((unsigned)type << 26);
    }
}

// ==== cooperative GEMM epilogue: 64-row shared stage, 1KB-contiguous nt stores
__device__ __forceinline__ void gemm_epilogue(
        char* smem, f32x4 (&acc)[4][4], const float* bbase, _Float16* propD,
        int t, size_t m0, int lane, int wid, int wr, int wc)
{
    float bv[4];
    #pragma unroll
    for (int n = 0; n < 4; ++n)
        bv[n] = bbase[(size_t)t * 256 + (wc << 6) + (n << 4) + (lane & 15)];

    const int q  = lane >> 4;
    const int li = lane & 15;
    const int cb = wid & 1;
    const int w2 = wid >> 1;

    #pragma unroll
    for (int ph = 0; ph < 2; ++ph){
        __syncthreads();
        if (wr == ph){
            #pragma unroll
            for (int m = 0; m < 4; ++m){
                #pragma unroll
                for (int n = 0; n < 4; ++n){
                    #pragma unroll
                    for (int j = 0; j < 4; ++j){
                        int lrow = (m << 4) + (q << 2) + j;
                        int b    = (((wc << 6) + (n << 4) + li) << 1) ^ (q << 5);
                        *(_Float16*)(smem + lrow * 512 + b) =
                            (_Float16)(acc[m][n][j] + bv[n]);
                    }
                }
            }
        }
        __syncthreads();
        #pragma unroll
        for (int it = 0; it < 4; ++it){
            int r4   = w2 + (it << 2);
            int lrow = (r4 << 2) + q;
            int b    = ((cb << 8) + (li << 4)) ^ ((r4 & 3) << 5);
            f16x8 v = *(const f16x8*)(smem + lrow * 512 + b);
            size_t grow = m0 + (size_t)(ph << 6) + (size_t)lrow;
            _Float16* dst = propD + ((size_t)(cb * NTYPES + t) * M_PAD + grow) * 128
                            + (li << 3);
            __builtin_nontemporal_store(v, (f16x8*)dst);
        }
    }
}

__device__ __forceinline__ void gemm_mfma_phase(
        char* smem, f32x4 (&acc)[4][4], int lane, int wr, int wc)
{
    _Float16* sA = (_Float16*)smem;
    _Float16* sB = (_Float16*)(smem + 16384);
    #pragma unroll
    for (int ks = 0; ks < 2; ++ks){
        int slot = (ks << 6) + ((lane >> 4) << 4);
        f16x8 af[4];
        #pragma unroll
        for (int m = 0; m < 4; ++m){
            int rA = (wr << 6) + (m << 4) + (lane & 15);
            af[m] = *(const f16x8*)((const char*)sA + rA * 128 + (slot ^ ((rA & 7) << 4)));
        }
        #pragma unroll
        for (int n = 0; n < 4; ++n){
            int rB = (wc << 6) + (n << 4) + (lane & 15);
            f16x8 bfr = *(const f16x8*)((const char*)sB + rB * 128 + (slot ^ ((rB & 7) << 4)));
            #pragma unroll
            for (int m = 0; m < 4; ++m)
                acc[m][n] = __builtin_amdgcn_mfma_f32_16x16x32_f16(af[m], bfr, acc[m][n], 0, 0, 0);
        }
    }
}

// ---- GEMM: all 6 types, A from fp16 Ap via global_load_lds -----------------
__global__ __launch_bounds__(512, 4) void gemm_ap(
        const _Float16* __restrict__ Ap,
        const _Float16* __restrict__ Bp,
        const float* __restrict__ bbase,
        _Float16* __restrict__ propD)
{
    __shared__ __align__(16) char smem[49152];
    const int bid = blockIdx.x;
    const int g   = bid / 48;
    const int r   = bid - g * 48;
    const int rp  = g * 8 + (r & 7);
    const int t   = r >> 3;
    if (rp >= 782) return;
    const int tid  = threadIdx.x;
    const int lane = tid & 63;
    const int wid  = tid >> 6;
    const int wr   = wid >> 2;
    const int wc   = wid & 3;
    const size_t m0 = (size_t)rp * 128;
    const _Float16* Bt = Bp + (size_t)t * 256 * 256;

    f32x4 acc[4][4];
    #pragma unroll
    for (int m = 0; m < 4; ++m)
        #pragma unroll
        for (int n = 0; n < 4; ++n)
            acc[m][n] = (f32x4){0.f, 0.f, 0.f, 0.f};

    const int sub  = lane >> 3;
    const int bib  = (lane & 7) << 4;
    const int soff = bib ^ (sub << 4);

    for (int kk = 0; kk < 4; ++kk){
        #pragma unroll
        for (int ci = 0; ci < 6; ++ci){
            int c = wid * 6 + ci;
            const char* gsrc;
            char* ldst;
            if (c < 16){
                gsrc = (const char*)(Ap + (m0 + (size_t)((c << 3) + sub)) * 256);
                ldst = (char*)smem + (c << 10);
            } else {
                int c2 = c - 16;
                gsrc = (const char*)(Bt + ((size_t)(c2 << 3) + sub) * 256);
                ldst = (char*)smem + 16384 + (c2 << 10);
            }
            __builtin_amdgcn_global_load_lds(
                (const __attribute__((address_space(1))) void*)(gsrc + (kk << 7) + soff),
                (__attribute__((address_space(3))) void*)ldst, 16, 0, 0);
        }
        __syncthreads();
        gemm_mfma_phase(smem, acc, lane, wr, wc);
        __syncthreads();
    }
    gemm_epilogue(smem, acc, bbase, propD, t, m0, lane, wid, wr, wc);
}

// ---- fallback GEMM: A reg-staged from fp32 x -------------------------------
__global__ __launch_bounds__(512, 4) void gemm_dx(
        const float* __restrict__ x,
        const _Float16* __restrict__ Bp,
        const float* __restrict__ bbase,
        _Float16* __restrict__ propD)
{
    __shared__ __align__(16) char smem[49152];
    _Float16* sA = (_Float16*)smem;
    const int bid = blockIdx.x;
    const int g   = bid / 48;
    const int r   = bid - g * 48;
    const int rp  = g * 8 + (r & 7);
    const int t   = r >> 3;
    if (rp >= 782) return;
    const int tid  = threadIdx.x;
    const int lane = tid & 63;
    const int wid  = tid >> 6;
    const int wr   = wid >> 2;
    const int wc   = wid & 3;
    const size_t m0 = (size_t)rp * 128;
    const _Float16* Bt = Bp + (size_t)t * 256 * 256;

    f32x4 acc[4][4];
    #pragma unroll
    for (int m = 0; m < 4; ++m)
        #pragma unroll
        for (int n = 0; n < 4; ++n)
            acc[m][n] = (f32x4){0.f, 0.f, 0.f, 0.f};

    const int sub  = lane >> 3;
    const int bib  = (lane & 7) << 4;
    const int soff = bib ^ (sub << 4);

    for (int kk = 0; kk < 4; ++kk){
        #pragma unroll
        for (int ci = 0; ci < 6; ++ci){
            int c = wid * 6 + ci;
            if (c < 16){
                int rr = (c << 3) + sub;
                size_t grow = m0 + (size_t)rr;
                f32x4 u0 = (f32x4){0.f,0.f,0.f,0.f};
                f32x4 u1 = (f32x4){0.f,0.f,0.f,0.f};
                if (grow < N_NODES){
                    const float* px = x + grow * 256 + (kk << 6) + ((lane & 7) << 3);
                    u0 = *(const f32x4*)px;
                    u1 = *(const f32x4*)(px + 4);
                }
                f16x8 hv;
                hv[0]=(_Float16)u0[0]; hv[1]=(_Float16)u0[1];
                hv[2]=(_Float16)u0[2]; hv[3]=(_Float16)u0[3];
                hv[4]=(_Float16)u1[0]; hv[5]=(_Float16)u1[1];
                hv[6]=(_Float16)u1[2]; hv[7]=(_Float16)u1[3];
                *(f16x8*)((char*)sA + rr * 128 + (bib ^ (sub << 4))) = hv;
            } else {
                int c2 = c - 16;
                const char* gsrc = (const char*)(Bt + ((size_t)(c2 << 3) + sub) * 256);
                char* ldst = (char*)smem + 16384 + (c2 << 10);
                __builtin_amdgcn_global_load_lds(
                    (const __attribute__((address_space(1))) void*)(gsrc + (kk << 7) + soff),
                    (__attribute__((address_space(3))) void*)ldst, 16, 0, 0);
            }
        }
        __syncthreads();
        gemm_mfma_phase(smem, acc, lane, wr, wc);
        __syncthreads();
    }
    gemm_epilogue(smem, acc, bbase, propD, t, m0, lane, wid, wr, wc);
}

// ---- dim-half aggregation: 8 copies, start-offsets + sentinel, ILP-4 -------
__global__ void aggregate(const _Float16* __restrict__ propD, const _Float16* __restrict__ gate,
                          const unsigned* __restrict__ packed,
                          const int* __restrict__ buf,
                          int dh, float* __restrict__ out)
{
    int tgt  = blockIdx.x * 4 + (threadIdx.x >> 6);
    int lane = threadIdx.x & 63;

    int st[8], P[9];
    P[0] = 0;
    #pragma unroll
    for (int c = 0; c < 8; ++c){
        int lin = c * N_NODES + tgt;
        int a0 = buf[lin];
        int a1 = buf[lin + 1];
        st[c] = a0;
        P[c + 1] = P[c] + (a1 - a0);
    }
    int n = P[8];

    const _Float16* pbase = propD + (size_t)dh * NTYPES * M_PAD * 128;
    const _Float16* gbase = gate + dh * 128;

    float a0x = 0.f, a0y = 0.f, a1x = 0.f, a1y = 0.f;
    float a2x = 0.f, a2y = 0.f, a3x = 0.f, a3y = 0.f;

    for (int c0 = 0; c0 < n; c0 += 64){
        int e = c0 + lane;
        int idx = st[0] + e;
        #pragma unroll
        for (int c = 1; c < 8; ++c)
            if (e >= P[c]) idx = st[c] + (e - P[c]);
        unsigned wv = (e < n) ? packed[idx] : 0u;
        int m = n - c0; if (m > 64) m = 64;
        int e2 = 0;
        for (; e2 + 3 < m; e2 += 4){
            unsigned w[4];
            #pragma unroll
            for (int j = 0; j < 4; ++j)
                w[j] = (unsigned)__builtin_amdgcn_readlane((int)wv, e2 + j);
            f16x2 pv[4], gv[4];
            #pragma unroll
            for (int j = 0; j < 4; ++j){
                int src = (int)(w[j] & 0x1FFFFu);
                int pz  = (int)((w[j] >> 17) & 0x1FFu);
                int ty  = (int)(w[j] >> 26);
                pv[j] = *(const f16x2*)(pbase + ((size_t)ty * M_PAD + (size_t)src) * 128 + lane * 2);
                gv[j] = *(const f16x2*)(gbase + (size_t)pz * 256 + lane * 2);
            }
            a0x += (float)pv[0][0] * (float)gv[0][0];
            a0y += (float)pv[0][1] * (float)gv[0][1];
            a1x += (float)pv[1][0] * (float)gv[1][0];
            a1y += (float)pv[1][1] * (float)gv[1][1];
            a2x += (float)pv[2][0] * (float)gv[2][0];
            a2y += (float)pv[2][1] * (float)gv[2][1];
            a3x += (float)pv[3][0] * (float)gv[3][0];
            a3y += (float)pv[3][1] * (float)gv[3][1];
        }
        for (; e2 < m; ++e2){
            unsigned w0 = (unsigned)__builtin_amdgcn_readlane((int)wv, e2);
            int src = (int)(w0 & 0x1FFFFu);
            int pz  = (int)((w0 >> 17) & 0x1FFu);
            int ty  = (int)(w0 >> 26);
            f16x2 pv = *(const f16x2*)(pbase + ((size_t)ty * M_PAD + (size_t)src) * 128 + lane * 2);
            f16x2 gv = *(const f16x2*)(gbase + (size_t)pz * 256 + lane * 2);
            a0x += (float)pv[0] * (float)gv[0];
            a0y += (float)pv[1] * (float)gv[1];
        }
    }
    a0x += a1x + a2x + a3x;
    a0y += a1y + a2y + a3y;
    float inv = ((n == 0) ? 1.0f : (float)n) + 1e-8f;
    float2 rr = make_float2(a0x / inv, a0y / inv);
    *(float2*)(out + (size_t)tgt * DIM + dh * 128 + lane * 2) = rr;
}

extern "C" void kernel_launch(void* const* d_in, const int* in_sizes, int n_in,
                              void* d_out, int out_size, void* d_ws, size_t ws_size,
                              hipStream_t stream)
{
    const float* x     = (const float*)d_in[0];
    const float* W     = (const float*)d_in[1];
    const float* b     = (const float*)d_in[2];
    const float* Wp    = (const float*)d_in[3];
    const float* bp    = (const float*)d_in[4];
    const int*   edges = (const int*)d_in[5];
    const int*   posl  = (const int*)d_in[6];
    float* out = (float*)d_out;

    char* ws = (char*)d_ws;
    size_t o = 0;
    auto alloc = [&](size_t bytes){ void* p = ws + o; o += (bytes + 255) & ~(size_t)255; return p; };

    _Float16* propD = (_Float16*)alloc((size_t)2 * NTYPES * M_PAD * 128 * 2);  // 307.5 MB
    _Float16* Bp    = (_Float16*)alloc((size_t)NTYPES * 256 * 256 * 2);
    _Float16* gate  = (_Float16*)alloc((size_t)512 * 256 * 2);
    int*      buf   = (int*)alloc((size_t)(NSCAN + 1) * 4);
    unsigned* packed= (unsigned*)alloc((size_t)TOTAL_E * 4);
    int*      bsum  = (int*)alloc((size_t)SCAN_BLKS * 4 + 256);
    int*      ssum  = (int*)alloc((size_t)SCAN_BLKS * 4 + 256);
    size_t common = o;

    size_t apBytes   = (size_t)M_PAD * 256 * 2;        // 51.25 MB
    size_t partBytes = (size_t)TOTAL_E * 8;            // 19.2 MB
    size_t c0Bytes   = (size_t)(NPART + 1) * 4;
    bool planP = (ws_size >= common + partBytes + 2 * c0Bytes + apBytes + (2u << 20));
    bool planA = !planP && (ws_size >= common + (size_t)NSCAN * 4 + apBytes + (1u << 20));

    if (planP){
        int2* part  = (int2*)alloc(partBytes);
        int*  cnt0  = (int*)alloc(c0Bytes);
        int*  off0  = (int*)alloc(c0Bytes);
        _Float16* Ap = (_Float16*)alloc(apBytes);

        prep_kernel<<<704 + 12512, 256, 0, stream>>>(x, Ap, W, Bp, Wp, bp, gate);
        part_count<<<125, 1024, 0, stream>>>(edges, cnt0);
        part_scan<<<1, 1024, 0, stream>>>(cnt0, off0);
        part_scatter<<<125, 1024, 0, stream>>>(edges, posl, off0, part);
        hist_lds2<<<64, 1024, 0, stream>>>(part, off0, buf);
        scan1_kernel<<<SCAN_BLKS, 256, 0, stream>>>(buf, bsum);
        scan2_kernel<<<1, 256, 0, stream>>>(bsum, ssum);
        scan3_kernel<<<3125, 256, 0, stream>>>(buf, ssum, nullptr);
        scatter_lds2<<<64, 1024, 0, stream>>>(part, off0, buf, packed);
        gemm_ap<<<GEMM_BLKS, 512, 0, stream>>>(Ap, Bp, b, propD);
    } else {
        int* cursor = (int*)alloc((size_t)NSCAN * 4);
        _Float16* Ap = planA ? (_Float16*)alloc(apBytes) : nullptr;
        int aBlk = planA ? 12512 : 0;

        hipMemsetAsync(buf, 0, (size_t)NSCAN * 4, stream);
        prep_kernel<<<704 + aBlk, 256, 0, stream>>>(x, Ap, W, Bp, Wp, bp, gate);
        hist_glob<<<1172, 256, 0, stream>>>(edges, buf);
        scan1_kernel<<<SCAN_BLKS, 256, 0, stream>>>(buf, bsum);
        scan2_kernel<<<1, 256, 0, stream>>>(bsum, ssum);
        scan3_kernel<<<3125, 256, 0, stream>>>(buf, ssum, cursor);
        scatter_glob<<<1172, 256, 0, stream>>>(edges, posl, cursor, packed);
        if (planA) gemm_ap<<<GEMM_BLKS, 512, 0, stream>>>(Ap, Bp, b, propD);
        else       gemm_dx<<<GEMM_BLKS, 512, 0, stream>>>(x, Bp, b, propD);
    }

    aggregate<<<25000, 256, 0, stream>>>(propD, gate, packed, buf, 0, out);
    aggregate<<<25000, 256, 0, stream>>>(propD, gate, packed, buf, 1, out);
}